// Round 6
// baseline (48.135 us; speedup 1.0000x reference)
//
#include <hip/hip_runtime.h>

// out[d][c][h][w] = (h < d) ? left[c][h][w] - right[c][h + 128 - d][w] : 0
// N=1, C=16, H=128, W=256, D=128. Output (1,128,16,128,256) fp32 = 256 MiB.
//
// Bijection: data row (d,c,h) <-> input-row pair (h, hs=h+128-d), h < hs.
// A wave caching 8 left + 8 right rows (1 row = 256 fp32 = one wave-wide
// float4) emits 64 output rows from 16 loads -> 4x read amortization.
//
// R5 lesson: 1056 blocks = 4.125/CU -> serial tail on 32 CUs. This version:
// EVERY wave stores exactly 64 rows (64 KiB); 4096 waves = 1024 blocks =
// exactly 4 blocks/CU co-resident (@ ~96 VGPR -> 16 waves/CU).
//   [0,1920)     full tiles i<j: 64 data rows
//   [1920,2176)  diag tiles i==j: 28 data rows + 36 zero rows
//   [2176,4096)  zero waves: 64 zero rows
// Zero region (h >= d) enumerated linearly by (d,c,h); 132096 = 1920*64+256*36.
// NOTE: nt-stores regressed twice (R2, R4) -> plain stores only.

typedef float f32x4 __attribute__((ext_vector_type(4)));

__device__ __forceinline__ void zero_fill(f32x4* __restrict__ out,
                                          int z, int n, int lane) {
    // decode linear zero-row index z -> (d,c,h); slice (d) has 16*(128-d) rows
    int d = 0;
    while (z >= 16 * (128 - d)) { z -= 16 * (128 - d); ++d; }
    const int len = 128 - d;
    int c = z / len;
    int h = d + (z - c * len);

    const f32x4 zero = {0.f, 0.f, 0.f, 0.f};
    int idx = ((d << 11) + (c << 7) + h) * 64 + lane;
    for (int k = 0; k < n; ++k) {
        out[idx] = zero;
        ++h; idx += 64;
        if (h == 128) {                       // wave-uniform branch
            if (++c == 16) { c = 0; ++d; }
            h = d;
            idx = ((d << 11) + (c << 7) + h) * 64 + lane;
        }
    }
}

__global__ __launch_bounds__(256) void CostDifference_kernel(
    const f32x4* __restrict__ left,
    const f32x4* __restrict__ right,
    f32x4* __restrict__ out)
{
    const int wave = (blockIdx.x << 2) | (threadIdx.x >> 6);
    const int lane = threadIdx.x & 63;

    if (wave < 1920) {
        // ---- full 8x8 row-pair tile, i < j: all 64 pairs valid ----
        const int c = wave & 15;
        int p = wave >> 4;                       // 0..119
        int i = 0;
        while (p >= 15 - i) { p -= 15 - i; ++i; }   // wave-uniform decode
        const int j = i + 1 + p;

        const int i8 = i << 3, j8 = j << 3;
        f32x4 L[8], R[8];
#pragma unroll
        for (int a = 0; a < 8; ++a) L[a] = left [(c * 128 + i8 + a) * 64 + lane];
#pragma unroll
        for (int b = 0; b < 8; ++b) R[b] = right[(c * 128 + j8 + b) * 64 + lane];

        // d = 128 + (i8+a) - (j8+b);  row = d*2048 + c*128 + (i8+a)
        const int base = (128 + i8 - j8) * 2048 + c * 128 + i8;
#pragma unroll
        for (int a = 0; a < 8; ++a) {
#pragma unroll
            for (int b = 0; b < 8; ++b) {
                const int row = base + a * 2049 - b * 2048;
                f32x4 o;
                o.x = L[a].x - R[b].x;
                o.y = L[a].y - R[b].y;
                o.z = L[a].z - R[b].z;
                o.w = L[a].w - R[b].w;
                out[row * 64 + lane] = o;
            }
        }
    } else if (wave < 2176) {
        // ---- diag tile i == j: 28 data rows (a<b) + 36 zero rows ----
        const int t = wave - 1920;               // 0..255
        const int c = t & 15;
        const int i8 = (t >> 4) << 3;
        f32x4 L[8], R[8];
#pragma unroll
        for (int a = 0; a < 8; ++a) L[a] = left [(c * 128 + i8 + a) * 64 + lane];
#pragma unroll
        for (int b = 0; b < 8; ++b) R[b] = right[(c * 128 + i8 + b) * 64 + lane];

        const int base = 128 * 2048 + c * 128 + i8;   // i8 - j8 == 0
#pragma unroll
        for (int a = 0; a < 8; ++a) {
#pragma unroll
            for (int b = 0; b < 8; ++b) {
                if (a < b) {
                    const int row = base + a * 2049 - b * 2048;
                    f32x4 o;
                    o.x = L[a].x - R[b].x;
                    o.y = L[a].y - R[b].y;
                    o.z = L[a].z - R[b].z;
                    o.w = L[a].w - R[b].w;
                    out[row * 64 + lane] = o;
                }
            }
        }
        zero_fill(out, 122880 + t * 36, 36, lane);
    } else {
        // ---- pure zero waves: 64 rows each from the linear zero pool ----
        const int zi = wave - 2176;              // 0..1919
        zero_fill(out, zi * 64, 64, lane);
    }
}

extern "C" void kernel_launch(void* const* d_in, const int* in_sizes, int n_in,
                              void* d_out, int out_size, void* d_ws, size_t ws_size,
                              hipStream_t stream) {
    const f32x4* left  = (const f32x4*)d_in[0];
    const f32x4* right = (const f32x4*)d_in[1];
    f32x4* out = (f32x4*)d_out;

    CostDifference_kernel<<<1024, 256, 0, stream>>>(left, right, out);
}

// Round 7
// 43.552 us; speedup vs baseline: 1.1052x; 1.1052x over previous
//
#include <hip/hip_runtime.h>

// out[d][c][h][w] = (h < d) ? left[c][h][w] - right[c][h + 128 - d][w] : 0
// N=1, C=16, H=128, W=256, D=128. Output (1,128,16,128,256) fp32 = 256 MiB.
//
// Bijection: data row (d,c,h) <-> input-row pair (h, hs=h+128-d), h < hs.
// A wave caching 8 left + 8 right rows (1 row = 256 fp32 = one wave-wide
// float4) emits 64 output rows from 16 loads -> 4x read amortization.
// Stores are emitted in DIAGONAL order (fixed a-b => same d-slice,
// consecutive h) so each wave writes 15 contiguous runs (up to 8 KiB)
// instead of 64 scattered 1 KiB granules -> DRAM row-buffer friendly.
// Zero region: slice pair (d,127-d) = 129 rows split 65/64 over two waves
// (R5 structure; R6's linear-pool decode regressed via branchy store loop).
// NOTE: nt-stores regressed twice (R2, R4) -> plain stores only.
//
// Wave plan (4224 waves = 1056 blocks x 4):
//   [0,1920)     full tiles i<j: 64 data rows
//   [1920,2176)  diag tiles i==j: 28 data rows
//   [2176,4224)  zero waves: ~64.5 rows each, contiguous runs

typedef float f32x4 __attribute__((ext_vector_type(4)));

__global__ __launch_bounds__(256) void CostDifference_kernel(
    const f32x4* __restrict__ left,
    const f32x4* __restrict__ right,
    f32x4* __restrict__ out)
{
    const int wave = (blockIdx.x << 2) | (threadIdx.x >> 6);
    const int lane = threadIdx.x & 63;

    if (wave < 1920) {
        // ---- full 8x8 row-pair tile, i < j: all 64 pairs valid ----
        const int c = wave & 15;
        int p = wave >> 4;                       // 0..119
        int i = 0;
        while (p >= 15 - i) { p -= 15 - i; ++i; }   // wave-uniform decode
        const int j = i + 1 + p;

        const int i8 = i << 3, j8 = j << 3;
        f32x4 L[8], R[8];
#pragma unroll
        for (int a = 0; a < 8; ++a) L[a] = left [(c * 128 + i8 + a) * 64 + lane];
#pragma unroll
        for (int b = 0; b < 8; ++b) R[b] = right[(c * 128 + j8 + b) * 64 + lane];

        // d = 128 + i8 - j8 + (a-b); row = d*2048 + c*128 + i8 + a
        // diagonal order: ab = a-b fixed -> same slice, consecutive h
        const int base = (128 + i8 - j8) * 2048 + c * 128 + i8;
#pragma unroll
        for (int ab = -7; ab <= 7; ++ab) {
            const int lo = ab > 0 ? ab : 0;
            const int hi = ab < 0 ? 7 + ab : 7;
#pragma unroll
            for (int a = lo; a <= hi; ++a) {
                const int b = a - ab;
                const int row = base + a + ab * 2048;
                f32x4 o;
                o.x = L[a].x - R[b].x;
                o.y = L[a].y - R[b].y;
                o.z = L[a].z - R[b].z;
                o.w = L[a].w - R[b].w;
                out[row * 64 + lane] = o;
            }
        }
    } else if (wave < 2176) {
        // ---- diag tile i == j: pairs a < b (28 rows), diagonal order ----
        const int t = wave - 1920;
        const int c = t & 15;
        const int i8 = (t >> 4) << 3;
        f32x4 L[8], R[8];
#pragma unroll
        for (int a = 0; a < 8; ++a) L[a] = left [(c * 128 + i8 + a) * 64 + lane];
#pragma unroll
        for (int b = 0; b < 8; ++b) R[b] = right[(c * 128 + i8 + b) * 64 + lane];

        const int base = 128 * 2048 + c * 128 + i8;   // i8 - j8 == 0
#pragma unroll
        for (int ab = -7; ab <= -1; ++ab) {
#pragma unroll
            for (int a = 0; a <= 7 + ab; ++a) {
                const int b = a - ab;
                const int row = base + a + ab * 2048;
                f32x4 o;
                o.x = L[a].x - R[b].x;
                o.y = L[a].y - R[b].y;
                o.z = L[a].z - R[b].z;
                o.w = L[a].w - R[b].w;
                out[row * 64 + lane] = o;
            }
        }
    } else {
        // ---- zero waves: slice pair (d, 127-d), 129 rows split 65/64 ----
        const int zw = wave - 2176;              // 0..2047
        const int c    = zw & 15;
        const int t    = zw >> 4;                // 0..127
        const int d    = t >> 1;                 // 0..63
        const int half = t & 1;
        const int d2   = 127 - d;
        const int n1   = 128 - d;                // zero rows in slice d
        const int start = half ? 65 : 0;
        const int end   = half ? 129 : 65;
        const f32x4 zero = {0.f, 0.f, 0.f, 0.f};

        // slice d: rows d+kk for kk in [start, min(end, n1))
        const int e1 = min(end, n1);
        int rb = (d * 2048 + c * 128 + d + start) * 64 + lane;
        for (int kk = start; kk < e1; ++kk, rb += 64) out[rb] = zero;

        // slice d2: rows d2+(kk-n1) for kk in [max(start, n1), end)
        const int s2 = max(start, n1);
        rb = (d2 * 2048 + c * 128 + d2 + (s2 - n1)) * 64 + lane;
        for (int kk = s2; kk < end; ++kk, rb += 64) out[rb] = zero;
    }
}

extern "C" void kernel_launch(void* const* d_in, const int* in_sizes, int n_in,
                              void* d_out, int out_size, void* d_ws, size_t ws_size,
                              hipStream_t stream) {
    const f32x4* left  = (const f32x4*)d_in[0];
    const f32x4* right = (const f32x4*)d_in[1];
    f32x4* out = (f32x4*)d_out;

    CostDifference_kernel<<<1056, 256, 0, stream>>>(left, right, out);
}